// Round 9
// baseline (136.383 us; speedup 1.0000x reference)
//
#include <hip/hip_runtime.h>
#include <stdint.h>

typedef unsigned int u32;
typedef unsigned short u16;
typedef __attribute__((ext_vector_type(8))) short v8s;   // 8 bf16 (4 VGPRs)
typedef __attribute__((ext_vector_type(4))) float v4f;   // 4 f32 acc

#define GN_EPS 1e-5f

// ---------- bf16 helpers (intermediates in ws are bf16) ----------
__device__ __forceinline__ float bflo(u32 u){ return __uint_as_float(u << 16); }
__device__ __forceinline__ float bfhi(u32 u){ return __uint_as_float(u & 0xffff0000u); }
__device__ __forceinline__ u16 f2bf(float f){
  u32 x = __float_as_uint(f);
  u32 r = (x + 0x7fffu + ((x >> 16) & 1u)) >> 16;   // RNE
  return (u16)r;
}
__device__ __forceinline__ u32 pack2(float a, float b){
  return (u32)f2bf(a) | ((u32)f2bf(b) << 16);
}
__device__ __forceinline__ void unpack8(const uint4 u, float* f){
  f[0]=bflo(u.x); f[1]=bfhi(u.x); f[2]=bflo(u.y); f[3]=bfhi(u.y);
  f[4]=bflo(u.z); f[5]=bfhi(u.z); f[6]=bflo(u.w); f[7]=bfhi(u.w);
}
// load 8 f32, return packed bf16 (4 u32)
__device__ __forceinline__ uint4 loadpack8(const float* __restrict__ p){
  float4 a = *(const float4*)p, b = *(const float4*)(p + 4);
  return make_uint4(pack2(a.x,a.y),pack2(a.z,a.w),pack2(b.x,b.y),pack2(b.z,b.w));
}

// batch accessor: int32 or int64 (little-endian low word)
__device__ __forceinline__ int getb(const int* __restrict__ b, int is64, int i){
  return b[is64 ? 2*i : i];
}

// =====================================================================
// K0: detect batch int-width (parallel).
// =====================================================================
__global__ __launch_bounds__(256) void k_detect(
    const int* __restrict__ batch, int n, int* __restrict__ flags)
{
  int i = blockIdx.x*256 + threadIdx.x;
  int bad = 0;
  if (i < n - 1 && batch[i] > batch[i + 1]) bad = 1;
  if (__builtin_amdgcn_ballot_w64(bad) != 0 && (threadIdx.x & 63) == 0)
    atomicOr(&flags[0], 1);
}

// =====================================================================
// K0b: CSR bounds. bounds[g] = first node of graph g; bounds[B] = N.
// =====================================================================
__global__ __launch_bounds__(256) void k_bounds(
    const int* __restrict__ batch, const int* __restrict__ flags,
    int N, int B, int* __restrict__ bounds)
{
  int i = blockIdx.x*256 + threadIdx.x;
  if (i >= N) return;
  const int is64 = flags[0];
  int b = getb(batch, is64, i);
  int prev = (i == 0) ? -1 : getb(batch, is64, i - 1);
  for (int g = prev + 1; g <= b; g++) bounds[g] = i;
  if (i == N - 1)
    for (int g = b + 1; g <= B; g++) bounds[g] = N;
}

// =====================================================================
// K1 (MFMA): y = x @ w_pre^T + b_pre, f32 out. 64x64 tile, 4 waves 2x2.
// =====================================================================
__global__ __launch_bounds__(256) void k_pre(
    const float* __restrict__ x, const float* __restrict__ wpre,
    const float* __restrict__ bpre, float* __restrict__ y, int N, int nbm)
{
  __shared__ __align__(16) u16 As[64*40];
  __shared__ __align__(16) u16 Bs[64*40];
  const int t = threadIdx.x;
  const int bm = blockIdx.x % nbm;
  const int bn = blockIdx.x / nbm;          // 0..3
  const int m_base = bm*64, n_base = bn*64;
  const int w = t >> 6, lane = t & 63;
  const int wm = (w >> 1)*32, wn = (w & 1)*32;
  const int fr = lane & 15, fk = lane >> 4;
  const int srow = t >> 2, scol = (t & 3)*8;

  v4f acc[2][2];
#pragma unroll
  for (int i = 0; i < 2; i++)
#pragma unroll
    for (int j = 0; j < 2; j++) acc[i][j] = (v4f){0.f,0.f,0.f,0.f};

  for (int k0 = 0; k0 < 256; k0 += 32) {
    __syncthreads();
    {
      int gm = m_base + srow;
      uint4 av = make_uint4(0u,0u,0u,0u);
      if (gm < N) av = loadpack8(x + (size_t)gm*256 + k0 + scol);
      *(uint4*)&As[srow*40 + scol] = av;
      uint4 bv = loadpack8(wpre + (size_t)(n_base + srow)*256 + k0 + scol);
      *(uint4*)&Bs[srow*40 + scol] = bv;
    }
    __syncthreads();
    v8s a0 = *(const v8s*)&As[(wm      + fr)*40 + fk*8];
    v8s a1 = *(const v8s*)&As[(wm + 16 + fr)*40 + fk*8];
    v8s b0 = *(const v8s*)&Bs[(wn      + fr)*40 + fk*8];
    v8s b1 = *(const v8s*)&Bs[(wn + 16 + fr)*40 + fk*8];
    acc[0][0] = __builtin_amdgcn_mfma_f32_16x16x32_bf16(a0,b0,acc[0][0],0,0,0);
    acc[0][1] = __builtin_amdgcn_mfma_f32_16x16x32_bf16(a0,b1,acc[0][1],0,0,0);
    acc[1][0] = __builtin_amdgcn_mfma_f32_16x16x32_bf16(a1,b0,acc[1][0],0,0,0);
    acc[1][1] = __builtin_amdgcn_mfma_f32_16x16x32_bf16(a1,b1,acc[1][1],0,0,0);
  }
#pragma unroll
  for (int nj = 0; nj < 2; nj++) {
    int col = n_base + wn + nj*16 + fr;
    float bpv = bpre[col];
#pragma unroll
    for (int mi = 0; mi < 2; mi++) {
#pragma unroll
      for (int r = 0; r < 4; r++) {
        int row = m_base + wm + mi*16 + fk*4 + r;
        if (row < N) y[(size_t)row*256 + col] = acc[mi][nj][r] + bpv;
      }
    }
  }
}

// =====================================================================
// K2: block = (group g, 256-node chunk). Weight reads wave-uniform.
// =====================================================================
__global__ __launch_bounds__(256) void k_gnqkv(
    const float* __restrict__ y, const float* __restrict__ wq,
    const float* __restrict__ wk, const float* __restrict__ wv,
    u16* __restrict__ qo, u16* __restrict__ ko, u16* __restrict__ vo, int N)
{
  __shared__ __align__(16) float wL[3*512];
  const int t = threadIdx.x;
  const int g = blockIdx.x & 15;
  const int c = blockIdx.x >> 4;
  {
    const float* srcs[3] = {wq, wk, wv};
#pragma unroll
    for (int tz = 0; tz < 3; tz++) {
      wL[tz*512 + t]       = srcs[tz][g*512 + t];
      wL[tz*512 + t + 256] = srcs[tz][g*512 + t + 256];
    }
  }
  __syncthreads();
  const int node = c*256 + t;
  if (node >= N) return;

  const float* yp = y + (size_t)node*256 + g*16;
  float4 v0 = *(const float4*)yp;
  float4 v1 = *(const float4*)(yp + 4);
  float4 v2 = *(const float4*)(yp + 8);
  float4 v3 = *(const float4*)(yp + 12);
  float a[16] = {v0.x,v0.y,v0.z,v0.w, v1.x,v1.y,v1.z,v1.w,
                 v2.x,v2.y,v2.z,v2.w, v3.x,v3.y,v3.z,v3.w};
  float mu = 0.f;
#pragma unroll
  for (int i = 0; i < 16; i++) mu += a[i];
  mu *= 0.0625f;
  float s2 = 0.f;
#pragma unroll
  for (int i = 0; i < 16; i++) { float d = a[i]-mu; s2 = fmaf(d,d,s2); }
  float inv = rsqrtf(s2*0.0625f + GN_EPS);
  float yn[16];
#pragma unroll
  for (int i = 0; i < 16; i++) yn[i] = (a[i]-mu)*inv;

  u16* outs[3] = {qo, ko, vo};
#pragma unroll
  for (int tz = 0; tz < 3; tz++) {
#pragma unroll
    for (int s = 0; s < 2; s++) {
      u32 p[8];
#pragma unroll
      for (int o = 0; o < 16; o++) {
        const float* row = &wL[tz*512 + (s*16 + o)*16];
        float4 W0 = *(const float4*)row;
        float4 W1 = *(const float4*)(row + 4);
        float4 W2 = *(const float4*)(row + 8);
        float4 W3 = *(const float4*)(row + 12);
        float w[16] = {W0.x,W0.y,W0.z,W0.w,W1.x,W1.y,W1.z,W1.w,
                       W2.x,W2.y,W2.z,W2.w,W3.x,W3.y,W3.z,W3.w};
        float d = 0.f;
#pragma unroll
        for (int i = 0; i < 16; i++) d = fmaf(yn[i], w[i], d);
        if (tz < 2) d = __expf(d*0.25f);
        if (o & 1) p[o>>1] |= (u32)f2bf(d) << 16;
        else       p[o>>1]  = (u32)f2bf(d);
      }
      u16* dst = outs[tz] + (size_t)node*512 + g*32 + s*16;
      *(uint4*)dst       = make_uint4(p[0],p[1],p[2],p[3]);
      *(uint4*)(dst + 8) = make_uint4(p[4],p[5],p[6],p[7]);
    }
  }
}

// =====================================================================
// K3 (sub-block split): 4 blocks per graph, each owns 8 of 32 heads.
// Phase 1: thread=(ns 0..3, nh 0..7, hp 0..7); node loop stride 4 with
//   explicit prefetch (next K/V loaded before current consumed).
// Reduce: 2 LDS slabs (row stride 20 f32, head stride 324 -> <=2-way
//   banks, 16B aligned), 2-step tree: {2,3}->{0,1}, {1}->{0}.
// Phase 2 (ns==0): out1 = kv+xres (f32) + bf16 copy to kvsL.
// Phase 3: thread=(node-slot 0..31, head 0..7); ~1 iter per graph.
// =====================================================================
__global__ __launch_bounds__(256) void k_segatt(
    const u16* __restrict__ xk, const u16* __restrict__ xv,
    const u16* __restrict__ xq, const float* __restrict__ xres,
    const int* __restrict__ bounds,
    float* __restrict__ out1, u16* __restrict__ att, int N)
{
  __shared__ __align__(16) float red[2*2592];   // 2 slabs [nh]*324+[h]*20
  __shared__ float ksred[2*130];
  __shared__ __align__(16) u16 kvsL[8*280];     // head stride 280 u16
  __shared__ float kssL[8*17];
  const int t = threadIdx.x;
  const int b  = blockIdx.x >> 2;
  const int H0 = (blockIdx.x & 3) * 8;
  const int lo = bounds[b], hi = bounds[b+1];
  const int ns = t >> 6, nh = (t >> 3) & 7, hp = t & 7;

  float kv[2][16];
#pragma unroll
  for (int r = 0; r < 2; r++)
#pragma unroll
    for (int v = 0; v < 16; v++) kv[r][v] = 0.f;
  float ks0 = 0.f, ks1 = 0.f;

  // ---- phase 1: prefetched direct-from-global accumulation ----
  const size_t koff = (size_t)(H0 + nh)*16 + 2*hp;
  const size_t voff = (size_t)(H0 + nh)*16;
  int node = lo + ns;
  u32 kw = 0; uint4 V0 = make_uint4(0,0,0,0), V1 = make_uint4(0,0,0,0);
  if (node < hi) {
    kw = *(const u32*) (xk + (size_t)node*512 + koff);
    V0 = *(const uint4*)(xv + (size_t)node*512 + voff);
    V1 = *(const uint4*)(xv + (size_t)node*512 + voff + 8);
  }
  while (node < hi) {
    int nxt = node + 4;
    u32 kwn = 0; uint4 V0n = make_uint4(0,0,0,0), V1n = make_uint4(0,0,0,0);
    if (nxt < hi) {
      kwn = *(const u32*) (xk + (size_t)nxt*512 + koff);
      V0n = *(const uint4*)(xv + (size_t)nxt*512 + voff);
      V1n = *(const uint4*)(xv + (size_t)nxt*512 + voff + 8);
    }
    float k0 = bflo(kw), k1 = bfhi(kw);
    float vf[16]; unpack8(V0, vf); unpack8(V1, vf + 8);
    ks0 += k0; ks1 += k1;
#pragma unroll
    for (int v = 0; v < 16; v++) {
      kv[0][v] = fmaf(k0, vf[v], kv[0][v]);
      kv[1][v] = fmaf(k1, vf[v], kv[1][v]);
    }
    kw = kwn; V0 = V0n; V1 = V1n; node = nxt;
  }

  // ---- reduce across 4 node-slots (2-step tree) ----
  if (ns >= 2) {
    float* s = &red[(ns - 2)*2592];
#pragma unroll
    for (int r = 0; r < 2; r++) {
      float* rp = &s[nh*324 + (2*hp + r)*20];
      *(float4*)rp       = make_float4(kv[r][0], kv[r][1], kv[r][2], kv[r][3]);
      *(float4*)(rp + 4) = make_float4(kv[r][4], kv[r][5], kv[r][6], kv[r][7]);
      *(float4*)(rp + 8) = make_float4(kv[r][8], kv[r][9], kv[r][10],kv[r][11]);
      *(float4*)(rp + 12)= make_float4(kv[r][12],kv[r][13],kv[r][14],kv[r][15]);
    }
    ksred[(ns-2)*130 + nh*16 + 2*hp]     = ks0;
    ksred[(ns-2)*130 + nh*16 + 2*hp + 1] = ks1;
  }
  __syncthreads();
  if (ns < 2) {
    const float* s = &red[ns*2592];
#pragma unroll
    for (int r = 0; r < 2; r++) {
      const float* rp = &s[nh*324 + (2*hp + r)*20];
      float4 R0 = *(const float4*)rp;
      float4 R1 = *(const float4*)(rp + 4);
      float4 R2 = *(const float4*)(rp + 8);
      float4 R3 = *(const float4*)(rp + 12);
      kv[r][0] += R0.x; kv[r][1] += R0.y; kv[r][2] += R0.z; kv[r][3] += R0.w;
      kv[r][4] += R1.x; kv[r][5] += R1.y; kv[r][6] += R1.z; kv[r][7] += R1.w;
      kv[r][8] += R2.x; kv[r][9] += R2.y; kv[r][10]+= R2.z; kv[r][11]+= R2.w;
      kv[r][12]+= R3.x; kv[r][13]+= R3.y; kv[r][14]+= R3.z; kv[r][15]+= R3.w;
    }
    ks0 += ksred[ns*130 + nh*16 + 2*hp];
    ks1 += ksred[ns*130 + nh*16 + 2*hp + 1];
  }
  __syncthreads();
  if (ns == 1) {
#pragma unroll
    for (int r = 0; r < 2; r++) {
      float* rp = &red[nh*324 + (2*hp + r)*20];
      *(float4*)rp       = make_float4(kv[r][0], kv[r][1], kv[r][2], kv[r][3]);
      *(float4*)(rp + 4) = make_float4(kv[r][4], kv[r][5], kv[r][6], kv[r][7]);
      *(float4*)(rp + 8) = make_float4(kv[r][8], kv[r][9], kv[r][10],kv[r][11]);
      *(float4*)(rp + 12)= make_float4(kv[r][12],kv[r][13],kv[r][14],kv[r][15]);
    }
    ksred[nh*16 + 2*hp]     = ks0;
    ksred[nh*16 + 2*hp + 1] = ks1;
  }
  __syncthreads();
  if (ns == 0) {
#pragma unroll
    for (int r = 0; r < 2; r++) {
      const float* rp = &red[nh*324 + (2*hp + r)*20];
      float4 R0 = *(const float4*)rp;
      float4 R1 = *(const float4*)(rp + 4);
      float4 R2 = *(const float4*)(rp + 8);
      float4 R3 = *(const float4*)(rp + 12);
      kv[r][0] += R0.x; kv[r][1] += R0.y; kv[r][2] += R0.z; kv[r][3] += R0.w;
      kv[r][4] += R1.x; kv[r][5] += R1.y; kv[r][6] += R1.z; kv[r][7] += R1.w;
      kv[r][8] += R2.x; kv[r][9] += R2.y; kv[r][10]+= R2.z; kv[r][11]+= R2.w;
      kv[r][12]+= R3.x; kv[r][13]+= R3.y; kv[r][14]+= R3.z; kv[r][15]+= R3.w;
    }
    ks0 += ksred[nh*16 + 2*hp];
    ks1 += ksred[nh*16 + 2*hp + 1];
    kssL[nh*17 + 2*hp]     = ks0;
    kssL[nh*17 + 2*hp + 1] = ks1;

    // ---- phase 2: out1 = kv + xres; bf16 copy into kvsL ----
#pragma unroll
    for (int r = 0; r < 2; r++) {
      int h = 2*hp + r;
      size_t idx = ((size_t)(b*32 + H0 + nh)*16 + h)*16;
      const float* xp = xres + idx;
      float4 X0 = *(const float4*)xp;
      float4 X1 = *(const float4*)(xp + 4);
      float4 X2 = *(const float4*)(xp + 8);
      float4 X3 = *(const float4*)(xp + 12);
      float xf[16] = {X0.x,X0.y,X0.z,X0.w,X1.x,X1.y,X1.z,X1.w,
                      X2.x,X2.y,X2.z,X2.w,X3.x,X3.y,X3.z,X3.w};
      float o[16];
#pragma unroll
      for (int j = 0; j < 16; j++) o[j] = kv[r][j] + xf[j];
      float* op = out1 + idx;
      *(float4*)op        = make_float4(o[0],o[1],o[2],o[3]);
      *(float4*)(op + 4)  = make_float4(o[4],o[5],o[6],o[7]);
      *(float4*)(op + 8)  = make_float4(o[8],o[9],o[10],o[11]);
      *(float4*)(op + 12) = make_float4(o[12],o[13],o[14],o[15]);
      u16* lp = &kvsL[nh*280 + h*16];
      *(uint4*)lp       = make_uint4(pack2(o[0],o[1]),  pack2(o[2],o[3]),
                                     pack2(o[4],o[5]),  pack2(o[6],o[7]));
      *(uint4*)(lp + 8) = make_uint4(pack2(o[8],o[9]),  pack2(o[10],o[11]),
                                     pack2(o[12],o[13]),pack2(o[14],o[15]));
    }
  }
  __syncthreads();

  // ---- phase 3: att, 32 node-slots x 8 heads ----
  const int nh2 = t & 7, ns2 = t >> 3;
  for (int n0 = lo; n0 < hi; n0 += 32) {
    int nodei = n0 + ns2;
    if (nodei >= hi) continue;
    const u16* qp = xq + (size_t)nodei*512 + (H0 + nh2)*16;
    uint4 Q0 = *(const uint4*)qp;
    uint4 Q1 = *(const uint4*)(qp + 8);
    float q[16]; unpack8(Q0, q); unpack8(Q1, q + 8);
    const float* ksp = &kssL[nh2*17];
    float denom = 0.f;
#pragma unroll
    for (int i = 0; i < 16; i++) denom = fmaf(q[i], ksp[i], denom);
    float inv = 1.0f / fmaxf(denom, 1e-20f);
    float a[16];
#pragma unroll
    for (int v = 0; v < 16; v++) a[v] = 0.f;
    const u16* kvp = &kvsL[nh2*280];
#pragma unroll
    for (int h = 0; h < 16; h++) {
      float qh = q[h] * inv;
      uint4 W0 = *(const uint4*)(kvp + h*16);
      uint4 W1 = *(const uint4*)(kvp + h*16 + 8);
      float w[16]; unpack8(W0, w); unpack8(W1, w + 8);
#pragma unroll
      for (int v = 0; v < 16; v++) a[v] = fmaf(qh, w[v], a[v]);
    }
    u32 p[8];
#pragma unroll
    for (int j = 0; j < 8; j++) p[j] = pack2(a[2*j], a[2*j+1]);
    u16* dst = att + (size_t)nodei*512 + (H0 + nh2)*16;
    *(uint4*)dst       = make_uint4(p[0],p[1],p[2],p[3]);
    *(uint4*)(dst + 8) = make_uint4(p[4],p[5],p[6],p[7]);
  }
}

// =====================================================================
// K5 (MFMA): out0 = exp(log_scale) * (att @ w_post^T + b_post), K=512.
// =====================================================================
__global__ __launch_bounds__(256) void k_post(
    const u16* __restrict__ att, const float* __restrict__ wpost,
    const float* __restrict__ bpost, const float* __restrict__ ls,
    float* __restrict__ out0, int N, int nbm)
{
  __shared__ __align__(16) u16 As[64*40];
  __shared__ __align__(16) u16 Bs[64*40];
  const int t = threadIdx.x;
  const int bm = blockIdx.x % nbm;
  const int bn = blockIdx.x / nbm;          // 0..3
  const int m_base = bm*64, n_base = bn*64;
  const int w = t >> 6, lane = t & 63;
  const int wm = (w >> 1)*32, wn = (w & 1)*32;
  const int fr = lane & 15, fk = lane >> 4;
  const int srow = t >> 2, scol = (t & 3)*8;

  v4f acc[2][2];
#pragma unroll
  for (int i = 0; i < 2; i++)
#pragma unroll
    for (int j = 0; j < 2; j++) acc[i][j] = (v4f){0.f,0.f,0.f,0.f};

  for (int k0 = 0; k0 < 512; k0 += 32) {
    __syncthreads();
    {
      int gm = m_base + srow;
      uint4 av = make_uint4(0u,0u,0u,0u);
      if (gm < N) av = *(const uint4*)(att + (size_t)gm*512 + k0 + scol);
      *(uint4*)&As[srow*40 + scol] = av;
      uint4 bv = loadpack8(wpost + (size_t)(n_base + srow)*512 + k0 + scol);
      *(uint4*)&Bs[srow*40 + scol] = bv;
    }
    __syncthreads();
    v8s a0 = *(const v8s*)&As[(wm      + fr)*40 + fk*8];
    v8s a1 = *(const v8s*)&As[(wm + 16 + fr)*40 + fk*8];
    v8s b0 = *(const v8s*)&Bs[(wn      + fr)*40 + fk*8];
    v8s b1 = *(const v8s*)&Bs[(wn + 16 + fr)*40 + fk*8];
    acc[0][0] = __builtin_amdgcn_mfma_f32_16x16x32_bf16(a0,b0,acc[0][0],0,0,0);
    acc[0][1] = __builtin_amdgcn_mfma_f32_16x16x32_bf16(a0,b1,acc[0][1],0,0,0);
    acc[1][0] = __builtin_amdgcn_mfma_f32_16x16x32_bf16(a1,b0,acc[1][0],0,0,0);
    acc[1][1] = __builtin_amdgcn_mfma_f32_16x16x32_bf16(a1,b1,acc[1][1],0,0,0);
  }
#pragma unroll
  for (int nj = 0; nj < 2; nj++) {
    int col = n_base + wn + nj*16 + fr;
    float bpv = bpost[col];
    float e   = __expf(ls[col]);
#pragma unroll
    for (int mi = 0; mi < 2; mi++) {
#pragma unroll
      for (int r = 0; r < 4; r++) {
        int row = m_base + wm + mi*16 + fk*4 + r;
        if (row < N) out0[(size_t)row*256 + col] = e*(acc[mi][nj][r] + bpv);
      }
    }
  }
}

// =====================================================================
extern "C" void kernel_launch(void* const* d_in, const int* in_sizes, int n_in,
                              void* d_out, int out_size, void* d_ws, size_t ws_size,
                              hipStream_t stream)
{
  const float* x     = (const float*)d_in[0];
  const float* xres  = (const float*)d_in[1];
  const int*   batch = (const int*)d_in[2];
  const float* wpre  = (const float*)d_in[4];
  const float* bpre  = (const float*)d_in[5];
  const float* wq    = (const float*)d_in[6];
  const float* wk    = (const float*)d_in[7];
  const float* wv    = (const float*)d_in[8];
  const float* wpost = (const float*)d_in[9];
  const float* bpost = (const float*)d_in[10];
  const float* ls    = (const float*)d_in[11];

  const int N = in_sizes[0] / 256;     // 20000 nodes
  const int B = in_sizes[1] / 8192;    // 1024 graphs
  const int nbm = (N + 63) / 64;       // 313 row tiles
  const int nchunk = (N + 255) / 256;  // 79 node chunks

  char* ws = (char*)d_ws;
  size_t off = 0;
  int*   flags  = (int*)(ws + off); off += 256;
  int*   bounds = (int*)(ws + off); off += ((size_t)B + 64) * 4;
  float* y      = (float*)(ws + off);                          // reused for att
  u16*   att    = (u16*)(ws + off);  off += (size_t)N * 1024;
  u16*   q      = (u16*)(ws + off);  off += (size_t)N * 1024;
  u16*   kten   = (u16*)(ws + off);  off += (size_t)N * 1024;
  u16*   vten   = (u16*)(ws + off);  off += (size_t)N * 1024;

  float* out0 = (float*)d_out;
  float* out1 = out0 + (size_t)N * 256;

  hipMemsetAsync(flags, 0, 4, stream);
  k_detect<<<nchunk,         256, 0, stream>>>(batch, N, flags);
  k_bounds<<<nchunk,         256, 0, stream>>>(batch, flags, N, B, bounds);
  k_pre   <<<nbm * 4,        256, 0, stream>>>(x, wpre, bpre, y, N, nbm);
  k_gnqkv <<<nchunk * 16,    256, 0, stream>>>(y, wq, wk, wv, q, kten, vten, N);
  k_segatt<<<B * 4,          256, 0, stream>>>(kten, vten, q, xres, bounds,
                                               out1, att, N);
  k_post  <<<nbm * 4,        256, 0, stream>>>(att, wpost, bpost, ls, out0, N, nbm);
}